// Round 5
// baseline (257.382 us; speedup 1.0000x reference)
//
#include <hip/hip_runtime.h>

// Sparse 3D conv, GATHER formulation — zero floating-point atomics.
// R3/R4 post-mortem: 43.2M global fp32 atomicAdds are the hard floor
// (~145us regardless of compute structure). Fix: one owner per output voxel.
//
// prep:       map[B*96^3] = -1 (dense voxel index grid), pack W -> bf16 B-frags.
// build_map:  map[site] = vi via atomicExch; duplicates chained via nxt[vi].
// gather:     each wave owns 4 tiles of 16 consecutive output voxels.
//             27 offsets: scalar (zi,yi) validity, 16-lane map lookup
//             (one 128B segment), masked feat gather + fp32 chain-sum of
//             duplicates, pack bf16 (v_perm round-half-up),
//             mfma_f32_16x16x32_bf16 into persistent C regs.
//             Epilogue: plain coalesced stores (covers all outputs -> no memset).

#define DGRID 96
#define DOUT 48
#define CIN 32
#define COUT 64
#define NOFF 27
#define NSITE (2 * DGRID * DGRID * DGRID)     // 1,769,472 sites (B=2)
#define WPACK_ELEMS (NOFF * 4 * 64 * 8)       // 55,296 bf16
#define NTILE (2 * DOUT * DOUT * DOUT / 16)   // 13,824 tiles of 16 outputs
#define TPW 4                                 // tiles per wave
#define NWAVE (NTILE / TPW)                   // 3,456 waves

typedef __attribute__((ext_vector_type(8))) short bf16x8;
typedef __attribute__((ext_vector_type(4))) float f32x4;

static __device__ __forceinline__ unsigned short f2bf_rne(float x) {
    unsigned u = __float_as_uint(x);
    u += 0x7fffu + ((u >> 16) & 1u);
    return (unsigned short)(u >> 16);
}

// Pack two fp32 -> bf16x2 with round-half-up (+0x8000 then take hi16).
// Same 2^-9 max-rel-error bound as RNE; 1 v_perm + 2 v_add per pair.
static __device__ __forceinline__ unsigned pk_bf16(float lo, float hi) {
    unsigned a = __float_as_uint(lo) + 0x8000u;
    unsigned b = __float_as_uint(hi) + 0x8000u;
    // bytes 0..3 = src1(a), 4..7 = src0(b); take a[3:2] then b[3:2]
    return __builtin_amdgcn_perm(b, a, 0x07060302u);
}

// ws layout: int map[NSITE] | int nxt[N] (padded to 16B) | bf16 Wpack

__global__ __launch_bounds__(256) void prep_kernel(
    const float* __restrict__ W, int* __restrict__ map,
    unsigned short* __restrict__ Wpack)
{
    const int tid = blockIdx.x * 256 + threadIdx.x;
    if (tid < NSITE / 4) {                       // 442,368 -> first 1728 blocks
        ((int4*)map)[tid] = make_int4(-1, -1, -1, -1);
        return;
    }
    const int w = tid - NSITE / 4;
    if (w < WPACK_ELEMS) {
        // Wpack[((o*4+f)*64+l)*8+j] = bf16(W[o][k][cout]),
        // k = (l>>4)*8 + j, cout = f*16 + (l&15).  (validated in R4)
        const int j = w & 7, l = (w >> 3) & 63, f = (w >> 9) & 3, o = w >> 11;
        const int k    = ((l >> 4) << 3) + j;
        const int cout = (f << 4) + (l & 15);
        Wpack[w] = f2bf_rne(W[(o * CIN + k) * COUT + cout]);
    }
}

__global__ __launch_bounds__(256) void build_map_kernel(
    const int* __restrict__ coors, int* __restrict__ map,
    int* __restrict__ nxt, int N)
{
    const int vi = blockIdx.x * 256 + threadIdx.x;
    if (vi >= N) return;
    const int b = coors[vi * 4 + 0];
    const int z = coors[vi * 4 + 1];
    const int y = coors[vi * 4 + 2];
    const int x = coors[vi * 4 + 3];
    const int site = ((b * DGRID + z) * DGRID + y) * DGRID + x;
    nxt[vi] = atomicExch(&map[site], vi);   // chain head swap (handles dups)
}

__global__ __launch_bounds__(256) void spconv_gather_kernel(
    const float* __restrict__ feat,   // [N, CIN] fp32
    const int*   __restrict__ map,    // [NSITE] voxel index or -1
    const int*   __restrict__ nxt,    // duplicate chains
    const unsigned short* __restrict__ Wpack,
    float*       __restrict__ out)    // [B*DOUT^3, COUT]
{
    const int lane  = threadIdx.x & 63;
    const int col   = lane & 15;      // output row within tile / C col
    const int khalf = lane >> 4;      // k-chunk for A-frag, row group for C
    const int wid   = blockIdx.x * 4 + (threadIdx.x >> 6);   // 0..NWAVE-1

    // Decode this wave's 4 tiles (wave-uniform -> SGPRs).
    int tb[TPW], tzo[TPW], tyo[TPW], txb[TPW];
#pragma unroll
    for (int t = 0; t < TPW; ++t) {
        const int tau = wid + t * NWAVE;
        const int x16 = tau % 3;
        const int r2  = tau / 3;
        tyo[t] = r2 % DOUT;
        const int r3 = r2 / DOUT;
        tzo[t] = r3 % DOUT;
        tb[t]  = r3 / DOUT;
        txb[t] = x16 << 4;
    }

    f32x4 acc[TPW][4];
#pragma unroll
    for (int t = 0; t < TPW; ++t)
#pragma unroll
        for (int q = 0; q < 4; ++q)
            acc[t][q] = (f32x4){0.f, 0.f, 0.f, 0.f};

    for (int off = 0; off < NOFF; ++off) {
        const int kx = off % 3;
        const int ky = (off / 3) % 3;
        const int kz = off / 9;
        // B-frags for this offset, amortized over TPW tiles.
        const bf16x8* wp = (const bf16x8*)Wpack + off * 256 + lane;
        const bf16x8 b0 = wp[0];
        const bf16x8 b1 = wp[64];
        const bf16x8 b2 = wp[128];
        const bf16x8 b3 = wp[192];

#pragma unroll
        for (int t = 0; t < TPW; ++t) {
            // input z/y for this (tile, offset): z_in = 2*zo - 1 + kz
            const int zi = 2 * tzo[t] - 1 + kz;
            const int yi = 2 * tyo[t] - 1 + ky;
            if ((unsigned)zi >= DGRID || (unsigned)yi >= DGRID) continue; // scalar

            const int xi = 2 * (txb[t] + col) - 1 + kx;    // per-lane (x stride 1)
            const int sbase = ((tb[t] * DGRID + zi) * DGRID + yi) * DGRID;
            int vi = -1;
            if ((unsigned)xi < DGRID) vi = map[sbase + xi];

            // fp32 sum over duplicate chain (almost always 0 or 1 iteration).
            float a0 = 0.f, a1 = 0.f, a2 = 0.f, a3 = 0.f;
            float a4 = 0.f, a5 = 0.f, a6 = 0.f, a7 = 0.f;
            while (vi >= 0) {
                const float4* fp = (const float4*)(feat + (size_t)vi * CIN + (khalf << 3));
                const float4 u = fp[0];
                const float4 v = fp[1];
                a0 += u.x; a1 += u.y; a2 += u.z; a3 += u.w;
                a4 += v.x; a5 += v.y; a6 += v.z; a7 += v.w;
                vi = nxt[vi];
            }
            union { unsigned u[4]; bf16x8 v8; } af;
            af.u[0] = pk_bf16(a0, a1);
            af.u[1] = pk_bf16(a2, a3);
            af.u[2] = pk_bf16(a4, a5);
            af.u[3] = pk_bf16(a6, a7);

            acc[t][0] = __builtin_amdgcn_mfma_f32_16x16x32_bf16(af.v8, b0, acc[t][0], 0, 0, 0);
            acc[t][1] = __builtin_amdgcn_mfma_f32_16x16x32_bf16(af.v8, b1, acc[t][1], 0, 0, 0);
            acc[t][2] = __builtin_amdgcn_mfma_f32_16x16x32_bf16(af.v8, b2, acc[t][2], 0, 0, 0);
            acc[t][3] = __builtin_amdgcn_mfma_f32_16x16x32_bf16(af.v8, b3, acc[t][3], 0, 0, 0);
        }
    }

    // Epilogue: plain stores. C layout: col = lane&15, row = khalf*4 + r.
    // Covers every output element exactly once -> also provides the zeros.
#pragma unroll
    for (int t = 0; t < TPW; ++t) {
        const int tau = wid + t * NWAVE;
        float* ob = out + (size_t)tau * 16 * COUT;
#pragma unroll
        for (int r = 0; r < 4; ++r) {
            float* op = ob + ((khalf << 2) + r) * COUT + col;
            op[0]  = acc[t][0][r];
            op[16] = acc[t][1][r];
            op[32] = acc[t][2][r];
            op[48] = acc[t][3][r];
        }
    }
}

extern "C" void kernel_launch(void* const* d_in, const int* in_sizes, int n_in,
                              void* d_out, int out_size, void* d_ws, size_t ws_size,
                              hipStream_t stream) {
    const float* feat  = (const float*)d_in[0];
    const int*   coors = (const int*)d_in[1];
    const float* W     = (const float*)d_in[3];
    float*       out   = (float*)d_out;

    const int N = in_sizes[0] / CIN;  // 200000

    int* map = (int*)d_ws;                                   // 7,077,888 B
    int* nxt = map + NSITE;                                  //   800,000 B
    unsigned short* Wpack = (unsigned short*)(nxt + ((N + 3) & ~3));  // 110,592 B (16B-aligned)

    // prep: map = -1, Wpack = bf16 B-frag layout. (No output memset needed:
    // gather kernel stores every output element.)
    const int prep_blocks = (NSITE / 4 + WPACK_ELEMS + 255) / 256;
    prep_kernel<<<prep_blocks, 256, 0, stream>>>(W, map, Wpack);

    build_map_kernel<<<(N + 255) / 256, 256, 0, stream>>>(coors, map, nxt, N);

    spconv_gather_kernel<<<NWAVE / 4, 256, 0, stream>>>(feat, map, nxt, Wpack, out);
}

// Round 6
// 194.998 us; speedup vs baseline: 1.3199x; 1.3199x over previous
//
#include <hip/hip_runtime.h>

// Sparse 3D conv, GATHER formulation — zero fp atomics (R5 structure).
// R5 post-mortem: correct structure, starved schedule (occupancy 19%,
// 864 blocks). R6: TPW 4->2 (6912 waves / 1728 blocks), ballot-skip of
// all-empty map rows. Everything else proven in R5.
//
// prep:       map[B*96^3] = -1, pack W -> bf16 MFMA B-frags.
// build_map:  map[site] = vi via atomicExch; duplicates chained via nxt[vi].
// gather:     each wave owns TPW tiles of 16 consecutive output voxels.
//             27 offsets: scalar (zi,yi) validity, 16-lane map lookup,
//             masked feat gather + fp32 chain-sum of duplicates, bf16 pack,
//             mfma_f32_16x16x32_bf16 into persistent C regs; plain stores.

#define DGRID 96
#define DOUT 48
#define CIN 32
#define COUT 64
#define NOFF 27
#define NSITE (2 * DGRID * DGRID * DGRID)     // 1,769,472 sites (B=2)
#define WPACK_ELEMS (NOFF * 4 * 64 * 8)       // 55,296 bf16
#define NTILE (2 * DOUT * DOUT * DOUT / 16)   // 13,824 tiles of 16 outputs
#define TPW 2                                 // tiles per wave
#define NWAVE (NTILE / TPW)                   // 6,912 waves -> 1728 blocks

typedef __attribute__((ext_vector_type(8))) short bf16x8;
typedef __attribute__((ext_vector_type(4))) float f32x4;

static __device__ __forceinline__ unsigned short f2bf_rne(float x) {
    unsigned u = __float_as_uint(x);
    u += 0x7fffu + ((u >> 16) & 1u);
    return (unsigned short)(u >> 16);
}

// Pack two fp32 -> bf16x2, round-half-up (same 2^-9 error bound as RNE).
static __device__ __forceinline__ unsigned pk_bf16(float lo, float hi) {
    unsigned a = __float_as_uint(lo) + 0x8000u;
    unsigned b = __float_as_uint(hi) + 0x8000u;
    return __builtin_amdgcn_perm(b, a, 0x07060302u);
}

// ws layout: int map[NSITE] | int nxt[N] (16B-aligned) | bf16 Wpack

__global__ __launch_bounds__(256) void prep_kernel(
    const float* __restrict__ W, int* __restrict__ map,
    unsigned short* __restrict__ Wpack)
{
    const int tid = blockIdx.x * 256 + threadIdx.x;
    if (tid < NSITE / 4) {
        ((int4*)map)[tid] = make_int4(-1, -1, -1, -1);
        return;
    }
    const int w = tid - NSITE / 4;
    if (w < WPACK_ELEMS) {
        // Wpack[((o*4+f)*64+l)*8+j] = bf16(W[o][k][cout]),
        // k = (l>>4)*8 + j, cout = f*16 + (l&15).  (validated R4/R5)
        const int j = w & 7, l = (w >> 3) & 63, f = (w >> 9) & 3, o = w >> 11;
        const int k    = ((l >> 4) << 3) + j;
        const int cout = (f << 4) + (l & 15);
        Wpack[w] = f2bf_rne(W[(o * CIN + k) * COUT + cout]);
    }
}

__global__ __launch_bounds__(256) void build_map_kernel(
    const int* __restrict__ coors, int* __restrict__ map,
    int* __restrict__ nxt, int N)
{
    const int vi = blockIdx.x * 256 + threadIdx.x;
    if (vi >= N) return;
    const int b = coors[vi * 4 + 0];
    const int z = coors[vi * 4 + 1];
    const int y = coors[vi * 4 + 2];
    const int x = coors[vi * 4 + 3];
    const int site = ((b * DGRID + z) * DGRID + y) * DGRID + x;
    nxt[vi] = atomicExch(&map[site], vi);   // chain head swap (handles dups)
}

__global__ __launch_bounds__(256) void spconv_gather_kernel(
    const float* __restrict__ feat,   // [N, CIN] fp32
    const int*   __restrict__ map,    // [NSITE] voxel index or -1
    const int*   __restrict__ nxt,    // duplicate chains
    const unsigned short* __restrict__ Wpack,
    float*       __restrict__ out)    // [B*DOUT^3, COUT]
{
    const int lane  = threadIdx.x & 63;
    const int col   = lane & 15;      // output row within tile / C col
    const int khalf = lane >> 4;      // k-chunk for A-frag, row group for C
    const int wid   = blockIdx.x * 4 + (threadIdx.x >> 6);   // 0..NWAVE-1

    // Decode this wave's tiles (wave-uniform -> SGPRs).
    int tb[TPW], tzo[TPW], tyo[TPW], txb[TPW];
#pragma unroll
    for (int t = 0; t < TPW; ++t) {
        const int tau = wid + t * NWAVE;
        const int x16 = tau % 3;
        const int r2  = tau / 3;
        tyo[t] = r2 % DOUT;
        const int r3 = r2 / DOUT;
        tzo[t] = r3 % DOUT;
        tb[t]  = r3 / DOUT;
        txb[t] = x16 << 4;
    }

    f32x4 acc[TPW][4];
#pragma unroll
    for (int t = 0; t < TPW; ++t)
#pragma unroll
        for (int q = 0; q < 4; ++q)
            acc[t][q] = (f32x4){0.f, 0.f, 0.f, 0.f};

    for (int off = 0; off < NOFF; ++off) {
        const int kx = off % 3;
        const int ky = (off / 3) % 3;
        const int kz = off / 9;
        // B-frags for this offset (L1-resident; shared by all waves).
        const bf16x8* wp = (const bf16x8*)Wpack + off * 256 + lane;
        const bf16x8 b0 = wp[0];
        const bf16x8 b1 = wp[64];
        const bf16x8 b2 = wp[128];
        const bf16x8 b3 = wp[192];

#pragma unroll
        for (int t = 0; t < TPW; ++t) {
            const int zi = 2 * tzo[t] - 1 + kz;
            const int yi = 2 * tyo[t] - 1 + ky;
            if ((unsigned)zi >= DGRID || (unsigned)yi >= DGRID) continue; // scalar

            const int xi = 2 * (txb[t] + col) - 1 + kx;    // per-lane
            const int sbase = ((tb[t] * DGRID + zi) * DGRID + yi) * DGRID;
            int vi = -1;
            if ((unsigned)xi < DGRID) vi = map[sbase + xi];

            // ~15% of rows have no active input at all -> skip everything.
            if (__ballot(vi >= 0) == 0ull) continue;

            // fp32 sum over duplicate chain (almost always 0/1 iteration).
            float a0 = 0.f, a1 = 0.f, a2 = 0.f, a3 = 0.f;
            float a4 = 0.f, a5 = 0.f, a6 = 0.f, a7 = 0.f;
            while (vi >= 0) {
                const float4* fp = (const float4*)(feat + (size_t)vi * CIN + (khalf << 3));
                const float4 u = fp[0];
                const float4 v = fp[1];
                a0 += u.x; a1 += u.y; a2 += u.z; a3 += u.w;
                a4 += v.x; a5 += v.y; a6 += v.z; a7 += v.w;
                vi = nxt[vi];
            }
            union { unsigned u[4]; bf16x8 v8; } af;
            af.u[0] = pk_bf16(a0, a1);
            af.u[1] = pk_bf16(a2, a3);
            af.u[2] = pk_bf16(a4, a5);
            af.u[3] = pk_bf16(a6, a7);

            acc[t][0] = __builtin_amdgcn_mfma_f32_16x16x32_bf16(af.v8, b0, acc[t][0], 0, 0, 0);
            acc[t][1] = __builtin_amdgcn_mfma_f32_16x16x32_bf16(af.v8, b1, acc[t][1], 0, 0, 0);
            acc[t][2] = __builtin_amdgcn_mfma_f32_16x16x32_bf16(af.v8, b2, acc[t][2], 0, 0, 0);
            acc[t][3] = __builtin_amdgcn_mfma_f32_16x16x32_bf16(af.v8, b3, acc[t][3], 0, 0, 0);
        }
    }

    // Epilogue: plain coalesced stores; covers every output element once
    // (also provides the zeros -> no output memset anywhere).
#pragma unroll
    for (int t = 0; t < TPW; ++t) {
        const int tau = wid + t * NWAVE;
        float* ob = out + (size_t)tau * 16 * COUT;
#pragma unroll
        for (int r = 0; r < 4; ++r) {
            float* op = ob + ((khalf << 2) + r) * COUT + col;
            op[0]  = acc[t][0][r];
            op[16] = acc[t][1][r];
            op[32] = acc[t][2][r];
            op[48] = acc[t][3][r];
        }
    }
}

extern "C" void kernel_launch(void* const* d_in, const int* in_sizes, int n_in,
                              void* d_out, int out_size, void* d_ws, size_t ws_size,
                              hipStream_t stream) {
    const float* feat  = (const float*)d_in[0];
    const int*   coors = (const int*)d_in[1];
    const float* W     = (const float*)d_in[3];
    float*       out   = (float*)d_out;

    const int N = in_sizes[0] / CIN;  // 200000

    int* map = (int*)d_ws;                                   // 7,077,888 B
    int* nxt = map + NSITE;                                  //   800,000 B
    unsigned short* Wpack = (unsigned short*)(nxt + ((N + 3) & ~3));  // 110,592 B

    const int prep_blocks = (NSITE / 4 + WPACK_ELEMS + 255) / 256;
    prep_kernel<<<prep_blocks, 256, 0, stream>>>(W, map, Wpack);

    build_map_kernel<<<(N + 255) / 256, 256, 0, stream>>>(coors, map, nxt, N);

    spconv_gather_kernel<<<NWAVE / 4, 256, 0, stream>>>(feat, map, nxt, Wpack, out);
}

// Round 7
// 157.895 us; speedup vs baseline: 1.6301x; 1.2350x over previous
//
#include <hip/hip_runtime.h>

// Sparse 3D conv, gather formulation, R7: software-pipelined map prefetch +
// pre-merged bf16 feature table.
//
// prep:       map[B*96^3] = -1, pack W -> bf16 MFMA B-frags.
// build_map:  map[site] = vi via atomicExch; duplicate chain via nxt[vi].
// merge_feat: chain heads get fp32-summed, bf16-packed feature rows (64 B).
// gather:     wave owns 2 tiles of 16 output voxels. Offset loop pipelines:
//             issue map row loads for off+1, gather bf16 feat rows for off
//             (one dwordx4/lane), 8 MFMA into persistent C regs. Plain
//             coalesced stores cover every output (no memset anywhere).

#define DGRID 96
#define DOUT 48
#define CIN 32
#define COUT 64
#define NOFF 27
#define NSITE (2 * DGRID * DGRID * DGRID)     // 1,769,472 sites (B=2)
#define WPACK_ELEMS (NOFF * 4 * 64 * 8)       // 55,296 bf16
#define NTILE (2 * DOUT * DOUT * DOUT / 16)   // 13,824 tiles of 16 outputs
#define TPW 2                                 // tiles per wave
#define NWAVE (NTILE / TPW)                   // 6,912 waves -> 1,728 blocks

typedef __attribute__((ext_vector_type(8))) short bf16x8;
typedef __attribute__((ext_vector_type(4))) float f32x4;

static __device__ __forceinline__ unsigned short f2bf_rne(float x) {
    unsigned u = __float_as_uint(x);
    u += 0x7fffu + ((u >> 16) & 1u);
    return (unsigned short)(u >> 16);
}

// Pack two fp32 -> bf16x2, round-half-up (same 2^-9 error bound as RNE).
static __device__ __forceinline__ unsigned pk_bf16(float lo, float hi) {
    unsigned a = __float_as_uint(lo) + 0x8000u;
    unsigned b = __float_as_uint(hi) + 0x8000u;
    return __builtin_amdgcn_perm(b, a, 0x07060302u);
}

// ws layout: int map[NSITE] | int nxt[N] (64B-pad) | bf16 featbf[N*CIN] | bf16 Wpack

__global__ __launch_bounds__(256) void prep_kernel(
    const float* __restrict__ W, int* __restrict__ map,
    unsigned short* __restrict__ Wpack)
{
    const int tid = blockIdx.x * 256 + threadIdx.x;
    if (tid < NSITE / 4) {
        ((int4*)map)[tid] = make_int4(-1, -1, -1, -1);
        return;
    }
    const int w = tid - NSITE / 4;
    if (w < WPACK_ELEMS) {
        // Wpack[((o*4+f)*64+l)*8+j] = bf16(W[o][k][cout]),
        // k = (l>>4)*8 + j, cout = f*16 + (l&15).  (validated R4-R6)
        const int j = w & 7, l = (w >> 3) & 63, f = (w >> 9) & 3, o = w >> 11;
        const int k    = ((l >> 4) << 3) + j;
        const int cout = (f << 4) + (l & 15);
        Wpack[w] = f2bf_rne(W[(o * CIN + k) * COUT + cout]);
    }
}

__global__ __launch_bounds__(256) void build_map_kernel(
    const int* __restrict__ coors, int* __restrict__ map,
    int* __restrict__ nxt, int N)
{
    const int vi = blockIdx.x * 256 + threadIdx.x;
    if (vi >= N) return;
    const int b = coors[vi * 4 + 0];
    const int z = coors[vi * 4 + 1];
    const int y = coors[vi * 4 + 2];
    const int x = coors[vi * 4 + 3];
    const int site = ((b * DGRID + z) * DGRID + y) * DGRID + x;
    nxt[vi] = atomicExch(&map[site], vi);   // chain head swap (handles dups)
}

// 8 threads per voxel (part = 4 channels each). Chain heads sum duplicate
// rows in fp32 and store a 64 B bf16 row; non-heads are never read.
__global__ __launch_bounds__(256) void merge_feat_kernel(
    const float* __restrict__ feat, const int* __restrict__ coors,
    const int* __restrict__ map, const int* __restrict__ nxt,
    unsigned short* __restrict__ featbf, int N)
{
    const int tid = blockIdx.x * 256 + threadIdx.x;
    const int vi = tid >> 3, part = tid & 7;
    if (vi >= N) return;
    const int b = coors[vi * 4 + 0];
    const int z = coors[vi * 4 + 1];
    const int y = coors[vi * 4 + 2];
    const int x = coors[vi * 4 + 3];
    const int site = ((b * DGRID + z) * DGRID + y) * DGRID + x;
    if (map[site] != vi) return;          // not a chain head
    float4 s = *(const float4*)(feat + (size_t)vi * CIN + part * 4);
    int v2 = nxt[vi];
    while (v2 >= 0) {                     // ~3% of voxels; usually 0 iters
        const float4 u = *(const float4*)(feat + (size_t)v2 * CIN + part * 4);
        s.x += u.x; s.y += u.y; s.z += u.z; s.w += u.w;
        v2 = nxt[v2];
    }
    uint2 p;
    p.x = pk_bf16(s.x, s.y);
    p.y = pk_bf16(s.z, s.w);
    *(uint2*)(featbf + (size_t)vi * CIN + part * 4) = p;
}

__global__ __launch_bounds__(256) void spconv_gather_kernel(
    const unsigned short* __restrict__ featbf,  // [N, CIN] bf16, chain-merged
    const int*            __restrict__ map,     // [NSITE] head voxel or -1
    const unsigned short* __restrict__ Wpack,   // bf16 B-frag layout
    float*                __restrict__ out)     // [B*DOUT^3, COUT]
{
    const int lane  = threadIdx.x & 63;
    const int col   = lane & 15;      // output row within tile / C col
    const int khalf = lane >> 4;      // k-chunk for A-frag, row group for C
    const int wid   = blockIdx.x * 4 + (threadIdx.x >> 6);   // 0..NWAVE-1

    // Decode this wave's tiles (wave-uniform -> SGPRs).
    int tb[TPW], tzo[TPW], tyo[TPW], txb[TPW];
#pragma unroll
    for (int t = 0; t < TPW; ++t) {
        const int tau = wid + t * NWAVE;
        const int x16 = tau % 3;
        const int r2  = tau / 3;
        tyo[t] = r2 % DOUT;
        const int r3 = r2 / DOUT;
        tzo[t] = r3 % DOUT;
        tb[t]  = r3 / DOUT;
        txb[t] = x16 << 4;
    }

    f32x4 acc[TPW][4];
#pragma unroll
    for (int t = 0; t < TPW; ++t)
#pragma unroll
        for (int q = 0; q < 4; ++q)
            acc[t][q] = (f32x4){0.f, 0.f, 0.f, 0.f};

    // Issue the map-row loads for kernel offset `off` (independent gathers).
    auto ldmap = [&](int off, int (&m)[TPW]) {
        const int kx = off % 3, ky = (off / 3) % 3, kz = off / 9;
#pragma unroll
        for (int t = 0; t < TPW; ++t) {
            const int zi = 2 * tzo[t] - 1 + kz;
            const int yi = 2 * tyo[t] - 1 + ky;
            int v = -1;
            if ((unsigned)zi < DGRID && (unsigned)yi < DGRID) {
                const int xi = 2 * (txb[t] + col) - 1 + kx;
                if ((unsigned)xi < DGRID)
                    v = map[((tb[t] * DGRID + zi) * DGRID + yi) * DGRID + xi];
            }
            m[t] = v;
        }
    };

    int mcur[TPW];
    ldmap(0, mcur);

    for (int off = 0; off < NOFF; ++off) {
        // B-frags for this offset (L1-hot after first wave).
        const bf16x8* wp = (const bf16x8*)Wpack + off * 256 + lane;
        const bf16x8 b0 = wp[0];
        const bf16x8 b1 = wp[64];
        const bf16x8 b2 = wp[128];
        const bf16x8 b3 = wp[192];

        // Pipeline: map loads for off+1 go in flight NOW, consumed next iter.
        int mnxt[TPW] = { -1, -1 };
        if (off + 1 < NOFF) ldmap(off + 1, mnxt);

        // Feat gathers for both tiles issue back-to-back (2 in flight).
        bf16x8 af[TPW];
        bool act[TPW];
#pragma unroll
        for (int t = 0; t < TPW; ++t) {
            act[t] = __ballot(mcur[t] >= 0) != 0ull;
            af[t] = (bf16x8)0;
            if (mcur[t] >= 0)
                af[t] = *(const bf16x8*)(featbf + (size_t)mcur[t] * CIN + (khalf << 3));
        }
#pragma unroll
        for (int t = 0; t < TPW; ++t) {
            if (!act[t]) continue;   // ~15% of rows entirely empty
            acc[t][0] = __builtin_amdgcn_mfma_f32_16x16x32_bf16(af[t], b0, acc[t][0], 0, 0, 0);
            acc[t][1] = __builtin_amdgcn_mfma_f32_16x16x32_bf16(af[t], b1, acc[t][1], 0, 0, 0);
            acc[t][2] = __builtin_amdgcn_mfma_f32_16x16x32_bf16(af[t], b2, acc[t][2], 0, 0, 0);
            acc[t][3] = __builtin_amdgcn_mfma_f32_16x16x32_bf16(af[t], b3, acc[t][3], 0, 0, 0);
        }
#pragma unroll
        for (int t = 0; t < TPW; ++t) mcur[t] = mnxt[t];
    }

    // Epilogue: plain coalesced stores; covers every output element once
    // (also provides the zeros -> no output memset anywhere).
    // C layout: col = lane&15, row = khalf*4 + r (HW-verified mapping).
#pragma unroll
    for (int t = 0; t < TPW; ++t) {
        const int tau = wid + t * NWAVE;
        float* ob = out + (size_t)tau * 16 * COUT;
#pragma unroll
        for (int r = 0; r < 4; ++r) {
            float* op = ob + ((khalf << 2) + r) * COUT + col;
            op[0]  = acc[t][0][r];
            op[16] = acc[t][1][r];
            op[32] = acc[t][2][r];
            op[48] = acc[t][3][r];
        }
    }
}

extern "C" void kernel_launch(void* const* d_in, const int* in_sizes, int n_in,
                              void* d_out, int out_size, void* d_ws, size_t ws_size,
                              hipStream_t stream) {
    const float* feat  = (const float*)d_in[0];
    const int*   coors = (const int*)d_in[1];
    const float* W     = (const float*)d_in[3];
    float*       out   = (float*)d_out;

    const int N = in_sizes[0] / CIN;  // 200000

    char* ws = (char*)d_ws;
    int* map = (int*)ws;                                        // 7,077,888 B
    int* nxt = (int*)(ws + (size_t)NSITE * 4);                  //   800,000 B
    const size_t featbf_off = (size_t)NSITE * 4 + (((size_t)N * 4 + 63) & ~(size_t)63);
    unsigned short* featbf = (unsigned short*)(ws + featbf_off);        // 12.8 MB
    const size_t wpack_off = featbf_off + (((size_t)N * CIN * 2 + 15) & ~(size_t)15);
    unsigned short* Wpack = (unsigned short*)(ws + wpack_off);          // 110,592 B
    // total ws use ~20.8 MB

    const int prep_blocks = (NSITE / 4 + WPACK_ELEMS + 255) / 256;
    prep_kernel<<<prep_blocks, 256, 0, stream>>>(W, map, Wpack);

    build_map_kernel<<<(N + 255) / 256, 256, 0, stream>>>(coors, map, nxt, N);

    merge_feat_kernel<<<(N * 8 + 255) / 256, 256, 0, stream>>>(
        feat, coors, map, nxt, featbf, N);

    spconv_gather_kernel<<<NWAVE / 4, 256, 0, stream>>>(featbf, map, Wpack, out);
}